// Round 7
// baseline (1445.491 us; speedup 1.0000x reference)
//
#include <hip/hip_runtime.h>
#include <hip/hip_bf16.h>

#define EPSV 1e-5f
#define SLOPE 0.1f
#define NB 64  // nodes per block in k_agg3

typedef __attribute__((ext_vector_type(8))) unsigned short ushort8v;

static __device__ inline unsigned short f2bf(float f) {
    __hip_bfloat16 b = __float2bfloat16(f);
    return *reinterpret_cast<unsigned short*>(&b);
}
static __device__ inline float bf2f(unsigned short u) {
    return __uint_as_float(((unsigned)u) << 16);
}

// ---------------- degree ----------------
__global__ __launch_bounds__(256) void k_count(const int* __restrict__ col,
                                               unsigned* __restrict__ cnt, int E) {
    int e = blockIdx.x * 256 + threadIdx.x;
    if (e < E) atomicAdd(&cnt[col[e]], 1u);
}

__global__ __launch_bounds__(256) void k_dinv(const unsigned* __restrict__ cnt,
                                              float* __restrict__ dinv, int N) {
    int n = blockIdx.x * 256 + threadIdx.x;
    if (n < N) dinv[n] = rsqrtf((float)cnt[n] + 2.0f);
}

// ---------------- exclusive scan (3 kernels, 1024-elem chunks) ----------------
__global__ __launch_bounds__(256) void k_chunk_sum(const unsigned* __restrict__ cnt, int N,
                                                   unsigned* __restrict__ bsum) {
    __shared__ unsigned ls[256];
    int base = blockIdx.x * 1024;
    unsigned s = 0;
    for (int i = threadIdx.x; i < 1024; i += 256) {
        int idx = base + i;
        if (idx < N) s += cnt[idx];
    }
    ls[threadIdx.x] = s;
    __syncthreads();
    for (int st = 128; st > 0; st >>= 1) {
        if (threadIdx.x < st) ls[threadIdx.x] += ls[threadIdx.x + st];
        __syncthreads();
    }
    if (threadIdx.x == 0) bsum[blockIdx.x] = ls[0];
}

__global__ void k_scan_bsum(unsigned* __restrict__ bsum, int nb) {
    if (threadIdx.x == 0 && blockIdx.x == 0) {
        unsigned acc = 0;
        for (int i = 0; i < nb; i++) { unsigned v = bsum[i]; bsum[i] = acc; acc += v; }
    }
}

__global__ __launch_bounds__(256) void k_scan_chunks(const unsigned* __restrict__ cnt, int N,
                                                     const unsigned* __restrict__ bsum,
                                                     int* __restrict__ off, int E) {
    __shared__ unsigned ls[256];
    int base = blockIdx.x * 1024;
    unsigned v[4];
    unsigned s = 0;
#pragma unroll
    for (int j = 0; j < 4; j++) {
        int idx = base + threadIdx.x * 4 + j;
        v[j] = (idx < N) ? cnt[idx] : 0u;
        s += v[j];
    }
    ls[threadIdx.x] = s;
    __syncthreads();
    if (threadIdx.x == 0) {
        unsigned acc = bsum[blockIdx.x];
        for (int i = 0; i < 256; i++) { unsigned t = ls[i]; ls[i] = acc; acc += t; }
    }
    __syncthreads();
    unsigned acc = ls[threadIdx.x];
#pragma unroll
    for (int j = 0; j < 4; j++) {
        int idx = base + threadIdx.x * 4 + j;
        if (idx < N) off[idx] = (int)acc;
        acc += v[j];
    }
    if (base + threadIdx.x * 4 <= N - 1 && N - 1 < base + threadIdx.x * 4 + 4) off[N] = E;
}

// ---------------- counting-sort placement: (row, norm, dst) grouped by col ----------------
__global__ __launch_bounds__(256) void k_place(const int* __restrict__ row,
                                               const int* __restrict__ col,
                                               const float* __restrict__ dinv,
                                               int* __restrict__ cursor,
                                               int4* __restrict__ spack, int E) {
    int e = blockIdx.x * 256 + threadIdx.x;
    if (e >= E) return;
    int r = row[e], c = col[e];
    int pos = atomicAdd(&cursor[c], 1);
    spack[pos] = make_int4(r, __float_as_int(dinv[r] * dinv[c]), c, 0);
}

// ---------------- GEMM: Y[N,128] = X[N,128] @ W[128,128] ----------------
// MODE 0: f32 in           -> bf16 out
// MODE 1: f32 in, BN+leaky -> bf16 out
// MODE 2: f32 in, +bias    -> f32 out
template <int MODE>
__global__ __launch_bounds__(256) void k_gemm_t(const float* __restrict__ X,
                                                const float* __restrict__ W,
                                                const float* __restrict__ sums, float invN,
                                                const float* __restrict__ bnw,
                                                const float* __restrict__ bnb,
                                                const float* __restrict__ bias,
                                                void* __restrict__ Yv, int N) {
    __shared__ float xs[64][132];
    __shared__ float sc[128], sb[128];
    const int tid = threadIdx.x;
    if (MODE == 1) {
        if (tid < 128) {
            float mu = sums[tid] * invN;
            float var = sums[128 + tid] * invN - mu * mu;
            float s = rsqrtf(var + EPSV) * bnw[tid];
            sc[tid] = s;
            sb[tid] = bnb[tid] - mu * s;
        }
        __syncthreads();
    }
    const int base = blockIdx.x * 64;
    for (int i = tid; i < 2048; i += 256) {
        int r = i >> 5, c4 = i & 31;
        int row = base + r; if (row >= N) row = N - 1;
        float4 v = ((const float4*)(X + (size_t)row * 128))[c4];
        if (MODE == 1) {
            int f = c4 * 4;
            v.x = fmaf(v.x, sc[f + 0], sb[f + 0]); v.x = v.x > 0.f ? v.x : SLOPE * v.x;
            v.y = fmaf(v.y, sc[f + 1], sb[f + 1]); v.y = v.y > 0.f ? v.y : SLOPE * v.y;
            v.z = fmaf(v.z, sc[f + 2], sb[f + 2]); v.z = v.z > 0.f ? v.z : SLOPE * v.z;
            v.w = fmaf(v.w, sc[f + 3], sb[f + 3]); v.w = v.w > 0.f ? v.w : SLOPE * v.w;
        }
        *(float4*)(&xs[r][c4 * 4]) = v;
    }
    __syncthreads();
    const int c0 = (tid & 31) * 4;
    const int rg = tid >> 5;
    float acc[8][4];
#pragma unroll
    for (int i = 0; i < 8; i++) { acc[i][0] = acc[i][1] = acc[i][2] = acc[i][3] = 0.f; }
    for (int k = 0; k < 128; k += 4) {
        float4 w0 = *(const float4*)(W + (size_t)(k + 0) * 128 + c0);
        float4 w1 = *(const float4*)(W + (size_t)(k + 1) * 128 + c0);
        float4 w2 = *(const float4*)(W + (size_t)(k + 2) * 128 + c0);
        float4 w3 = *(const float4*)(W + (size_t)(k + 3) * 128 + c0);
#pragma unroll
        for (int i = 0; i < 8; i++) {
            float4 a = *(const float4*)(&xs[rg + 8 * i][k]);
            acc[i][0] = fmaf(a.x, w0.x, fmaf(a.y, w1.x, fmaf(a.z, w2.x, fmaf(a.w, w3.x, acc[i][0]))));
            acc[i][1] = fmaf(a.x, w0.y, fmaf(a.y, w1.y, fmaf(a.z, w2.y, fmaf(a.w, w3.y, acc[i][1]))));
            acc[i][2] = fmaf(a.x, w0.z, fmaf(a.y, w1.z, fmaf(a.z, w2.z, fmaf(a.w, w3.z, acc[i][2]))));
            acc[i][3] = fmaf(a.x, w0.w, fmaf(a.y, w1.w, fmaf(a.z, w2.w, fmaf(a.w, w3.w, acc[i][3]))));
        }
    }
#pragma unroll
    for (int i = 0; i < 8; i++) {
        int row = base + rg + 8 * i;
        if (row < N) {
            if (MODE == 2) {
                float4 o = make_float4(acc[i][0] + bias[c0], acc[i][1] + bias[c0 + 1],
                                       acc[i][2] + bias[c0 + 2], acc[i][3] + bias[c0 + 3]);
                ((float4*)((float*)Yv + (size_t)row * 128))[tid & 31] = o;
            } else {
                ushort4 o;
                o.x = f2bf(acc[i][0]); o.y = f2bf(acc[i][1]);
                o.z = f2bf(acc[i][2]); o.w = f2bf(acc[i][3]);
                ((ushort4*)((unsigned short*)Yv + (size_t)row * 128))[tid & 31] = o;
            }
        }
    }
}

// ---------------- CSR aggregation: block owns NB nodes, LDS accumulation ----------------
// edge-parallel: 16 groups x 16 lanes, no loop-carried register dependency
__global__ __launch_bounds__(256) void k_agg3(const unsigned short* __restrict__ xwh,
                                              const int* __restrict__ off,
                                              const int4* __restrict__ spack,
                                              const float* __restrict__ dinv,
                                              const float* __restrict__ bias,
                                              float* __restrict__ h,
                                              float* __restrict__ sums, int N) {
    __shared__ float acc[NB * 128];      // 32 KB
    __shared__ float ls1[256], ls2[256];
    const int tid = threadIdx.x;
    const int n0 = blockIdx.x * NB;
    const int nEnd = min(n0 + NB, N);
    for (int i = tid; i < NB * 128; i += 256) acc[i] = 0.f;
    __syncthreads();

    const int eBeg = off[n0], eEnd = off[nEnd];
    const int q = tid & 15;   // lane in group
    const int g = tid >> 4;   // group 0..15

    int i = eBeg + g;
    if (i < eEnd) {
        int4 p = spack[i];
        ushort8v v = *(const ushort8v*)(xwh + (size_t)p.x * 128 + q * 8);
        for (i += 16; i < eEnd; i += 16) {
            int4 pn = spack[i];
            ushort8v vn = *(const ushort8v*)(xwh + (size_t)pn.x * 128 + q * 8);  // in flight
            float nm = __int_as_float(p.y);
            float* dst = acc + (p.z - n0) * 128 + q * 8;
#pragma unroll
            for (int j = 0; j < 8; j++) {
                int jj = (j + q) & 7;  // stagger LDS banks across lanes
                __hip_atomic_fetch_add(dst + jj, nm * bf2f(v[jj]),
                                       __ATOMIC_RELAXED, __HIP_MEMORY_SCOPE_WORKGROUP);
            }
            p = pn; v = vn;
        }
        float nm = __int_as_float(p.y);
        float* dst = acc + (p.z - n0) * 128 + q * 8;
#pragma unroll
        for (int j = 0; j < 8; j++) {
            int jj = (j + q) & 7;
            __hip_atomic_fetch_add(dst + jj, nm * bf2f(v[jj]),
                                   __ATOMIC_RELAXED, __HIP_MEMORY_SCOPE_WORKGROUP);
        }
    }
    __syncthreads();

    // epilogue: self-loop + bias + write h + BN stats
    const int f = tid & 127;
    const float bj = bias[f];
    float s1 = 0.f, s2 = 0.f;
    for (int idx = tid; idx < (nEnd - n0) * 128; idx += 256) {
        int node = n0 + (idx >> 7);
        float d = dinv[node];
        float xv = bf2f(xwh[(size_t)node * 128 + f]);
        float o = acc[idx] + 2.f * d * d * xv + bj;
        h[(size_t)node * 128 + f] = o;
        s1 += o; s2 += o * o;
    }
    ls1[tid] = s1; ls2[tid] = s2;
    __syncthreads();
    if (tid < 128) {
        atomicAdd(&sums[f], ls1[tid] + ls1[tid + 128]);
        atomicAdd(&sums[128 + f], ls2[tid] + ls2[tid + 128]);
    }
}

// ---------------- pooling with fused BN2 + leaky ----------------
__global__ __launch_bounds__(256) void k_pool_init(unsigned* __restrict__ p, int total) {
    int i = blockIdx.x * 256 + threadIdx.x;
    if (i < total) p[i] = 0x007FFFFFu;  // encoded -inf
}

__device__ inline unsigned enc_f(float x) {
    unsigned u = __float_as_uint(x);
    return (u & 0x80000000u) ? ~u : (u | 0x80000000u);
}

__global__ __launch_bounds__(256) void k_pool2(const float* __restrict__ h,
                                               const int* __restrict__ batch,
                                               const float* __restrict__ sums, float invN,
                                               const float* __restrict__ bnw,
                                               const float* __restrict__ bnb,
                                               unsigned* __restrict__ pooled, int N) {
    const int f = threadIdx.x & 127;
    const int half = threadIdx.x >> 7;
    float mu = sums[f] * invN;
    float var = sums[128 + f] * invN - mu * mu;
    float scale = rsqrtf(var + EPSV) * bnw[f];
    float bias = bnb[f] - mu * scale;
    const int base = blockIdx.x * 128;
    const int end = min(base + 128, N);
    float m = -__builtin_inff();
    int g = -1;
    for (int n = base + half; n < end; n += 2) {
        int bg = batch[n];
        if (bg != g) {
            if (g >= 0) atomicMax(&pooled[(size_t)g * 128 + f], enc_f(m));
            g = bg;
            m = -__builtin_inff();
        }
        float v = fmaf(h[(size_t)n * 128 + f], scale, bias);
        v = v > 0.f ? v : SLOPE * v;
        m = fmaxf(m, v);
    }
    if (g >= 0) atomicMax(&pooled[(size_t)g * 128 + f], enc_f(m));
}

__global__ __launch_bounds__(256) void k_decode(unsigned* __restrict__ p, int total) {
    int i = blockIdx.x * 256 + threadIdx.x;
    if (i >= total) return;
    unsigned u = p[i];
    float v;
    if (u == 0x007FFFFFu) v = 0.f;  // empty graph (-inf) -> 0
    else if (u & 0x80000000u) v = __uint_as_float(u & 0x7FFFFFFFu);
    else v = __uint_as_float(~u);
    p[i] = __float_as_uint(v);
}

extern "C" void kernel_launch(void* const* d_in, const int* in_sizes, int n_in,
                              void* d_out, int out_size, void* d_ws, size_t ws_size,
                              hipStream_t stream) {
    const float* x     = (const float*)d_in[0];
    const int*   ei    = (const int*)d_in[1];
    const int*   batch = (const int*)d_in[2];
    const float* W1    = (const float*)d_in[3];
    const float* b1    = (const float*)d_in[4];
    const float* bn1w  = (const float*)d_in[5];
    const float* bn1b  = (const float*)d_in[6];
    const float* W2    = (const float*)d_in[7];
    const float* b2    = (const float*)d_in[8];
    const float* bn2w  = (const float*)d_in[9];
    const float* bn2b  = (const float*)d_in[10];
    const float* Wf    = (const float*)d_in[11];
    const float* bf    = (const float*)d_in[12];

    const int N = in_sizes[0] / 128;
    const int E = in_sizes[1] / 2;
    const int G = out_size / 128;
    const int* rowp = ei;
    const int* colp = ei + E;
    float* out = (float*)d_out;
    const float invN = 1.0f / N;

    char* w = (char*)d_ws;
    unsigned short* bufAh = (unsigned short*)w; w += (size_t)N * 128 * 2;  // bf16 xw
    float*    bufB   = (float*)w;    w += (size_t)N * 128 * 4;             // f32 h
    float*    dinv   = (float*)w;    w += (size_t)N * 4;
    unsigned* cnt    = (unsigned*)w; w += (size_t)N * 4;                   // reused as cursor
    int*      off    = (int*)w;      w += (size_t)(N + 4) * 4;             // padded for alignment
    unsigned* bsum   = (unsigned*)w; w += 1024 * 4;
    int4*     spack  = (int4*)w;     w += (size_t)E * 16;
    float*    sums   = (float*)w;    w += 512 * 4;                         // sums1 | sums2
    unsigned* pooled = (unsigned*)w; w += (size_t)G * 128 * 4;

    float* sums1 = sums;
    float* sums2 = sums + 256;
    const int nb = (N + 1023) / 1024;

    // ---- graph prep (once, reused by both layers) ----
    hipMemsetAsync(cnt, 0, (size_t)N * 4, stream);
    hipMemsetAsync(sums, 0, 512 * 4, stream);
    k_count<<<(E + 255) / 256, 256, 0, stream>>>(colp, cnt, E);
    k_dinv<<<(N + 255) / 256, 256, 0, stream>>>(cnt, dinv, N);
    k_chunk_sum<<<nb, 256, 0, stream>>>(cnt, N, bsum);
    k_scan_bsum<<<1, 64, 0, stream>>>(bsum, nb);
    k_scan_chunks<<<nb, 256, 0, stream>>>(cnt, N, bsum, off, E);
    hipMemcpyAsync(cnt, off, (size_t)N * 4, hipMemcpyDeviceToDevice, stream);  // cursor
    k_place<<<(E + 255) / 256, 256, 0, stream>>>(rowp, colp, dinv, (int*)cnt, spack, E);

    const int aggGrid = (N + NB - 1) / NB;

    // ---- layer 1 ----
    k_gemm_t<0><<<(N + 63) / 64, 256, 0, stream>>>(x, W1, nullptr, 0.f, nullptr, nullptr,
                                                   nullptr, bufAh, N);
    k_agg3<<<aggGrid, 256, 0, stream>>>(bufAh, off, spack, dinv, b1, bufB, sums1, N);

    // ---- layer 2 (BN1 fused into GEMM staging) ----
    k_gemm_t<1><<<(N + 63) / 64, 256, 0, stream>>>(bufB, W2, sums1, invN, bn1w, bn1b,
                                                   nullptr, bufAh, N);
    k_agg3<<<aggGrid, 256, 0, stream>>>(bufAh, off, spack, dinv, b2, bufB, sums2, N);

    // ---- pooling (BN2 fused) ----
    k_pool_init<<<(G * 128 + 255) / 256, 256, 0, stream>>>(pooled, G * 128);
    k_pool2<<<(N + 127) / 128, 256, 0, stream>>>(bufB, batch, sums2, invN, bn2w, bn2b,
                                                 pooled, N);
    k_decode<<<(G * 128 + 255) / 256, 256, 0, stream>>>(pooled, G * 128);

    // ---- final GEMM ----
    k_gemm_t<2><<<(G + 63) / 64, 256, 0, stream>>>((const float*)pooled, Wf, nullptr, 0.f,
                                                   nullptr, nullptr, bf, out, G);
}

// Round 8
// 1308.067 us; speedup vs baseline: 1.1051x; 1.1051x over previous
//
#include <hip/hip_runtime.h>
#include <hip/hip_bf16.h>

#define EPSV 1e-5f
#define SLOPE 0.1f

typedef __attribute__((ext_vector_type(8))) unsigned short ushort8v;

static __device__ inline unsigned short f2bf(float f) {
    __hip_bfloat16 b = __float2bfloat16(f);
    return *reinterpret_cast<unsigned short*>(&b);
}
static __device__ inline float bf2f(unsigned short u) {
    return __uint_as_float(((unsigned)u) << 16);
}

// ---------------- degree ----------------
__global__ __launch_bounds__(256) void k_count(const int* __restrict__ col,
                                               unsigned* __restrict__ cnt, int E) {
    int e = blockIdx.x * 256 + threadIdx.x;
    if (e < E) atomicAdd(&cnt[col[e]], 1u);
}

__global__ __launch_bounds__(256) void k_dinv(const unsigned* __restrict__ cnt,
                                              float* __restrict__ dinv, int N) {
    int n = blockIdx.x * 256 + threadIdx.x;
    if (n < N) dinv[n] = rsqrtf((float)cnt[n] + 2.0f);
}

// ---------------- exclusive scan (3 kernels, 1024-elem chunks) ----------------
__global__ __launch_bounds__(256) void k_chunk_sum(const unsigned* __restrict__ cnt, int N,
                                                   unsigned* __restrict__ bsum) {
    __shared__ unsigned ls[256];
    int base = blockIdx.x * 1024;
    unsigned s = 0;
    for (int i = threadIdx.x; i < 1024; i += 256) {
        int idx = base + i;
        if (idx < N) s += cnt[idx];
    }
    ls[threadIdx.x] = s;
    __syncthreads();
    for (int st = 128; st > 0; st >>= 1) {
        if (threadIdx.x < st) ls[threadIdx.x] += ls[threadIdx.x + st];
        __syncthreads();
    }
    if (threadIdx.x == 0) bsum[blockIdx.x] = ls[0];
}

__global__ void k_scan_bsum(unsigned* __restrict__ bsum, int nb) {
    if (threadIdx.x == 0 && blockIdx.x == 0) {
        unsigned acc = 0;
        for (int i = 0; i < nb; i++) { unsigned v = bsum[i]; bsum[i] = acc; acc += v; }
    }
}

__global__ __launch_bounds__(256) void k_scan_chunks(const unsigned* __restrict__ cnt, int N,
                                                     const unsigned* __restrict__ bsum,
                                                     int* __restrict__ off, int E) {
    __shared__ unsigned ls[256];
    int base = blockIdx.x * 1024;
    unsigned v[4];
    unsigned s = 0;
#pragma unroll
    for (int j = 0; j < 4; j++) {
        int idx = base + threadIdx.x * 4 + j;
        v[j] = (idx < N) ? cnt[idx] : 0u;
        s += v[j];
    }
    ls[threadIdx.x] = s;
    __syncthreads();
    if (threadIdx.x == 0) {
        unsigned acc = bsum[blockIdx.x];
        for (int i = 0; i < 256; i++) { unsigned t = ls[i]; ls[i] = acc; acc += t; }
    }
    __syncthreads();
    unsigned acc = ls[threadIdx.x];
#pragma unroll
    for (int j = 0; j < 4; j++) {
        int idx = base + threadIdx.x * 4 + j;
        if (idx < N) off[idx] = (int)acc;
        acc += v[j];
    }
    if (base + threadIdx.x * 4 <= N - 1 && N - 1 < base + threadIdx.x * 4 + 4) off[N] = E;
}

// ---------------- counting-sort placement: (row, norm, dst) grouped by col ----------------
__global__ __launch_bounds__(256) void k_place(const int* __restrict__ row,
                                               const int* __restrict__ col,
                                               const float* __restrict__ dinv,
                                               int* __restrict__ cursor,
                                               int4* __restrict__ spack, int E) {
    int e = blockIdx.x * 256 + threadIdx.x;
    if (e >= E) return;
    int r = row[e], c = col[e];
    int pos = atomicAdd(&cursor[c], 1);
    spack[pos] = make_int4(r, __float_as_int(dinv[r] * dinv[c]), c, 0);
}

// ---------------- GEMM: Y[N,128] = X[N,128] @ W[128,128] ----------------
// MODE 0: f32 in           -> bf16 out
// MODE 1: f32 in, BN+leaky -> bf16 out
// MODE 2: f32 in, +bias    -> f32 out
template <int MODE>
__global__ __launch_bounds__(256) void k_gemm_t(const float* __restrict__ X,
                                                const float* __restrict__ W,
                                                const float* __restrict__ sums, float invN,
                                                const float* __restrict__ bnw,
                                                const float* __restrict__ bnb,
                                                const float* __restrict__ bias,
                                                void* __restrict__ Yv, int N) {
    __shared__ float xs[64][132];
    __shared__ float sc[128], sb[128];
    const int tid = threadIdx.x;
    if (MODE == 1) {
        if (tid < 128) {
            float mu = sums[tid] * invN;
            float var = sums[128 + tid] * invN - mu * mu;
            float s = rsqrtf(var + EPSV) * bnw[tid];
            sc[tid] = s;
            sb[tid] = bnb[tid] - mu * s;
        }
        __syncthreads();
    }
    const int base = blockIdx.x * 64;
    for (int i = tid; i < 2048; i += 256) {
        int r = i >> 5, c4 = i & 31;
        int row = base + r; if (row >= N) row = N - 1;
        float4 v = ((const float4*)(X + (size_t)row * 128))[c4];
        if (MODE == 1) {
            int f = c4 * 4;
            v.x = fmaf(v.x, sc[f + 0], sb[f + 0]); v.x = v.x > 0.f ? v.x : SLOPE * v.x;
            v.y = fmaf(v.y, sc[f + 1], sb[f + 1]); v.y = v.y > 0.f ? v.y : SLOPE * v.y;
            v.z = fmaf(v.z, sc[f + 2], sb[f + 2]); v.z = v.z > 0.f ? v.z : SLOPE * v.z;
            v.w = fmaf(v.w, sc[f + 3], sb[f + 3]); v.w = v.w > 0.f ? v.w : SLOPE * v.w;
        }
        *(float4*)(&xs[r][c4 * 4]) = v;
    }
    __syncthreads();
    const int c0 = (tid & 31) * 4;
    const int rg = tid >> 5;
    float acc[8][4];
#pragma unroll
    for (int i = 0; i < 8; i++) { acc[i][0] = acc[i][1] = acc[i][2] = acc[i][3] = 0.f; }
    for (int k = 0; k < 128; k += 4) {
        float4 w0 = *(const float4*)(W + (size_t)(k + 0) * 128 + c0);
        float4 w1 = *(const float4*)(W + (size_t)(k + 1) * 128 + c0);
        float4 w2 = *(const float4*)(W + (size_t)(k + 2) * 128 + c0);
        float4 w3 = *(const float4*)(W + (size_t)(k + 3) * 128 + c0);
#pragma unroll
        for (int i = 0; i < 8; i++) {
            float4 a = *(const float4*)(&xs[rg + 8 * i][k]);
            acc[i][0] = fmaf(a.x, w0.x, fmaf(a.y, w1.x, fmaf(a.z, w2.x, fmaf(a.w, w3.x, acc[i][0]))));
            acc[i][1] = fmaf(a.x, w0.y, fmaf(a.y, w1.y, fmaf(a.z, w2.y, fmaf(a.w, w3.y, acc[i][1]))));
            acc[i][2] = fmaf(a.x, w0.z, fmaf(a.y, w1.z, fmaf(a.z, w2.z, fmaf(a.w, w3.z, acc[i][2]))));
            acc[i][3] = fmaf(a.x, w0.w, fmaf(a.y, w1.w, fmaf(a.z, w2.w, fmaf(a.w, w3.w, acc[i][3]))));
        }
    }
#pragma unroll
    for (int i = 0; i < 8; i++) {
        int row = base + rg + 8 * i;
        if (row < N) {
            if (MODE == 2) {
                float4 o = make_float4(acc[i][0] + bias[c0], acc[i][1] + bias[c0 + 1],
                                       acc[i][2] + bias[c0 + 2], acc[i][3] + bias[c0 + 3]);
                ((float4*)((float*)Yv + (size_t)row * 128))[tid & 31] = o;
            } else {
                ushort4 o;
                o.x = f2bf(acc[i][0]); o.y = f2bf(acc[i][1]);
                o.z = f2bf(acc[i][2]); o.w = f2bf(acc[i][3]);
                ((ushort4*)((unsigned short*)Yv + (size_t)row * 128))[tid & 31] = o;
            }
        }
    }
}

// ---------------- h init: self-loop + bias ----------------
__global__ __launch_bounds__(256) void k_init(const unsigned short* __restrict__ xwh,
                                              const float* __restrict__ dinv,
                                              const float* __restrict__ bias,
                                              float* __restrict__ h, int N) {
    const int total = N * 32;
    for (int idx = blockIdx.x * 256 + threadIdx.x; idx < total; idx += gridDim.x * 256) {
        int n = idx >> 5, c4 = idx & 31;
        float d = dinv[n];
        float sl = 2.f * d * d;
        ushort4 xv = ((const ushort4*)xwh)[(size_t)n * 32 + c4];
        float4 b4 = ((const float4*)bias)[c4];
        float4 o;
        o.x = fmaf(sl, bf2f(xv.x), b4.x);
        o.y = fmaf(sl, bf2f(xv.y), b4.y);
        o.z = fmaf(sl, bf2f(xv.z), b4.z);
        o.w = fmaf(sl, bf2f(xv.w), b4.w);
        ((float4*)h)[(size_t)n * 32 + c4] = o;
    }
}

// ---------------- edge-parallel aggregation with batched gathers ----------------
// 16-lane group owns a contiguous chunk of C CSR-sorted edges; register
// run-accumulation; atomicAdd flush on dst change. Lane q covers feats q*8..q*8+7.
__global__ __launch_bounds__(256) void k_agg4(const unsigned short* __restrict__ xwh,
                                              const int4* __restrict__ spack,
                                              float* __restrict__ h,
                                              int E, int C) {
    const int q = threadIdx.x & 15;
    const int gid = (blockIdx.x * 256 + threadIdx.x) >> 4;
    long long s0 = (long long)gid * C;
    if (s0 >= E) return;
    int base = (int)s0;
    const int i1 = (int)min((long long)E, s0 + C);

    float a[8] = {0, 0, 0, 0, 0, 0, 0, 0};
    int cur = -1;

    auto flushf = [&](int node) {
        float* dst = h + (size_t)node * 128 + q * 8;
#pragma unroll
        for (int j = 0; j < 8; j++) { atomicAdd(dst + j, a[j]); a[j] = 0.f; }
    };
    auto accum = [&](int nmbits, ushort8v v) {
        float nm = __int_as_float(nmbits);
#pragma unroll
        for (int j = 0; j < 8; j++) a[j] = fmaf(nm, bf2f(v[j]), a[j]);
    };

    // fast path: 16 edges per batch, gathers issued 8-at-a-time
    for (; base + 16 <= i1; base += 16) {
        int4 pl = spack[base + q];  // lane q holds edge base+q
#pragma unroll
        for (int half = 0; half < 2; half++) {
            int rr[8], nn[8], dd[8];
#pragma unroll
            for (int k = 0; k < 8; k++) {
                int src = half * 8 + k;
                rr[k] = __shfl(pl.x, src, 16);
                nn[k] = __shfl(pl.y, src, 16);
                dd[k] = __shfl(pl.z, src, 16);
            }
            ushort8v vv[8];
#pragma unroll
            for (int k = 0; k < 8; k++)
                vv[k] = *(const ushort8v*)(xwh + (size_t)rr[k] * 128 + q * 8);
#pragma unroll
            for (int k = 0; k < 8; k++) {
                if (dd[k] != cur) { if (cur >= 0) flushf(cur); cur = dd[k]; }
                accum(nn[k], vv[k]);
            }
        }
    }
    // tail (< 16 edges)
    for (; base < i1; ++base) {
        int4 p = spack[base];
        ushort8v v = *(const ushort8v*)(xwh + (size_t)p.x * 128 + q * 8);
        if (p.z != cur) { if (cur >= 0) flushf(cur); cur = p.z; }
        accum(p.y, v);
    }
    if (cur >= 0) flushf(cur);
}

// ---------------- BN statistics over h ----------------
__global__ __launch_bounds__(256) void k_stats(const float* __restrict__ h,
                                               float* __restrict__ sums, int N) {
    __shared__ float ss1[128], ss2[128];
    const int tid = threadIdx.x;
    if (tid < 128) { ss1[tid] = 0.f; ss2[tid] = 0.f; }
    __syncthreads();
    const int c4 = tid & 31;  // idx % 32 == c4 throughout (strides are multiples of 32)
    float s1[4] = {0, 0, 0, 0}, s2[4] = {0, 0, 0, 0};
    const int total = N * 32;
    for (int idx = blockIdx.x * 256 + tid; idx < total; idx += gridDim.x * 256) {
        float4 v = ((const float4*)h)[idx];
        s1[0] += v.x; s2[0] += v.x * v.x;
        s1[1] += v.y; s2[1] += v.y * v.y;
        s1[2] += v.z; s2[2] += v.z * v.z;
        s1[3] += v.w; s2[3] += v.w * v.w;
    }
#pragma unroll
    for (int j = 0; j < 4; j++) {
        atomicAdd(&ss1[c4 * 4 + j], s1[j]);
        atomicAdd(&ss2[c4 * 4 + j], s2[j]);
    }
    __syncthreads();
    if (tid < 128) {
        atomicAdd(&sums[tid], ss1[tid]);
        atomicAdd(&sums[128 + tid], ss2[tid]);
    }
}

// ---------------- pooling with fused BN2 + leaky ----------------
__global__ __launch_bounds__(256) void k_pool_init(unsigned* __restrict__ p, int total) {
    int i = blockIdx.x * 256 + threadIdx.x;
    if (i < total) p[i] = 0x007FFFFFu;  // encoded -inf
}

__device__ inline unsigned enc_f(float x) {
    unsigned u = __float_as_uint(x);
    return (u & 0x80000000u) ? ~u : (u | 0x80000000u);
}

__global__ __launch_bounds__(256) void k_pool2(const float* __restrict__ h,
                                               const int* __restrict__ batch,
                                               const float* __restrict__ sums, float invN,
                                               const float* __restrict__ bnw,
                                               const float* __restrict__ bnb,
                                               unsigned* __restrict__ pooled, int N) {
    const int f = threadIdx.x & 127;
    const int half = threadIdx.x >> 7;
    float mu = sums[f] * invN;
    float var = sums[128 + f] * invN - mu * mu;
    float scale = rsqrtf(var + EPSV) * bnw[f];
    float bias = bnb[f] - mu * scale;
    const int base = blockIdx.x * 128;
    const int end = min(base + 128, N);
    float m = -__builtin_inff();
    int g = -1;
    for (int n = base + half; n < end; n += 2) {
        int bg = batch[n];
        if (bg != g) {
            if (g >= 0) atomicMax(&pooled[(size_t)g * 128 + f], enc_f(m));
            g = bg;
            m = -__builtin_inff();
        }
        float v = fmaf(h[(size_t)n * 128 + f], scale, bias);
        v = v > 0.f ? v : SLOPE * v;
        m = fmaxf(m, v);
    }
    if (g >= 0) atomicMax(&pooled[(size_t)g * 128 + f], enc_f(m));
}

__global__ __launch_bounds__(256) void k_decode(unsigned* __restrict__ p, int total) {
    int i = blockIdx.x * 256 + threadIdx.x;
    if (i >= total) return;
    unsigned u = p[i];
    float v;
    if (u == 0x007FFFFFu) v = 0.f;  // empty graph (-inf) -> 0
    else if (u & 0x80000000u) v = __uint_as_float(u & 0x7FFFFFFFu);
    else v = __uint_as_float(~u);
    p[i] = __float_as_uint(v);
}

extern "C" void kernel_launch(void* const* d_in, const int* in_sizes, int n_in,
                              void* d_out, int out_size, void* d_ws, size_t ws_size,
                              hipStream_t stream) {
    const float* x     = (const float*)d_in[0];
    const int*   ei    = (const int*)d_in[1];
    const int*   batch = (const int*)d_in[2];
    const float* W1    = (const float*)d_in[3];
    const float* b1    = (const float*)d_in[4];
    const float* bn1w  = (const float*)d_in[5];
    const float* bn1b  = (const float*)d_in[6];
    const float* W2    = (const float*)d_in[7];
    const float* b2    = (const float*)d_in[8];
    const float* bn2w  = (const float*)d_in[9];
    const float* bn2b  = (const float*)d_in[10];
    const float* Wf    = (const float*)d_in[11];
    const float* bf    = (const float*)d_in[12];

    const int N = in_sizes[0] / 128;
    const int E = in_sizes[1] / 2;
    const int G = out_size / 128;
    const int* rowp = ei;
    const int* colp = ei + E;
    float* out = (float*)d_out;
    const float invN = 1.0f / N;

    char* w = (char*)d_ws;
    unsigned short* bufAh = (unsigned short*)w; w += (size_t)N * 128 * 2;  // bf16 xw
    float*    bufB   = (float*)w;    w += (size_t)N * 128 * 4;             // f32 h
    float*    dinv   = (float*)w;    w += (size_t)N * 4;
    unsigned* cnt    = (unsigned*)w; w += (size_t)N * 4;                   // reused as cursor
    int*      off    = (int*)w;      w += (size_t)(N + 4) * 4;
    unsigned* bsum   = (unsigned*)w; w += 1024 * 4;
    int4*     spack  = (int4*)w;     w += (size_t)E * 16;
    float*    sums   = (float*)w;    w += 512 * 4;                         // sums1 | sums2
    unsigned* pooled = (unsigned*)w; w += (size_t)G * 128 * 4;

    float* sums1 = sums;
    float* sums2 = sums + 256;
    const int nb = (N + 1023) / 1024;

    // ---- graph prep (once, reused by both layers) ----
    hipMemsetAsync(cnt, 0, (size_t)N * 4, stream);
    hipMemsetAsync(sums, 0, 512 * 4, stream);
    k_count<<<(E + 255) / 256, 256, 0, stream>>>(colp, cnt, E);
    k_dinv<<<(N + 255) / 256, 256, 0, stream>>>(cnt, dinv, N);
    k_chunk_sum<<<nb, 256, 0, stream>>>(cnt, N, bsum);
    k_scan_bsum<<<1, 64, 0, stream>>>(bsum, nb);
    k_scan_chunks<<<nb, 256, 0, stream>>>(cnt, N, bsum, off, E);
    hipMemcpyAsync(cnt, off, (size_t)N * 4, hipMemcpyDeviceToDevice, stream);  // cursor
    k_place<<<(E + 255) / 256, 256, 0, stream>>>(rowp, colp, dinv, (int*)cnt, spack, E);

    const int aggBlocks = 2048;
    const int nGroups = aggBlocks * 16;
    const int C = (E + nGroups - 1) / nGroups;  // edges per 16-lane group

    // ---- layer 1 ----
    k_gemm_t<0><<<(N + 63) / 64, 256, 0, stream>>>(x, W1, nullptr, 0.f, nullptr, nullptr,
                                                   nullptr, bufAh, N);
    k_init<<<2048, 256, 0, stream>>>(bufAh, dinv, b1, bufB, N);
    k_agg4<<<aggBlocks, 256, 0, stream>>>(bufAh, spack, bufB, E, C);
    k_stats<<<1024, 256, 0, stream>>>(bufB, sums1, N);

    // ---- layer 2 (BN1 fused into GEMM staging) ----
    k_gemm_t<1><<<(N + 63) / 64, 256, 0, stream>>>(bufB, W2, sums1, invN, bn1w, bn1b,
                                                   nullptr, bufAh, N);
    k_init<<<2048, 256, 0, stream>>>(bufAh, dinv, b2, bufB, N);
    k_agg4<<<aggBlocks, 256, 0, stream>>>(bufAh, spack, bufB, E, C);
    k_stats<<<1024, 256, 0, stream>>>(bufB, sums2, N);

    // ---- pooling (BN2 fused) ----
    k_pool_init<<<(G * 128 + 255) / 256, 256, 0, stream>>>(pooled, G * 128);
    k_pool2<<<(N + 127) / 128, 256, 0, stream>>>(bufB, batch, sums2, invN, bn2w, bn2b,
                                                 pooled, N);
    k_decode<<<(G * 128 + 255) / 256, 256, 0, stream>>>(pooled, G * 128);

    // ---- final GEMM ----
    k_gemm_t<2><<<(G + 63) / 64, 256, 0, stream>>>((const float*)pooled, Wf, nullptr, 0.f,
                                                   nullptr, nullptr, bf, out, G);
}

// Round 10
// 497.202 us; speedup vs baseline: 2.9073x; 2.6309x over previous
//
#include <hip/hip_runtime.h>
#include <hip/hip_bf16.h>

#define EPSV 1e-5f
#define SLOPE 0.1f

typedef __attribute__((ext_vector_type(8))) unsigned short ushort8v;

static __device__ inline unsigned short f2bf(float f) {
    __hip_bfloat16 b = __float2bfloat16(f);
    return *reinterpret_cast<unsigned short*>(&b);
}
static __device__ inline float bf2f(unsigned short u) {
    return __uint_as_float(((unsigned)u) << 16);
}

// ---------------- degree ----------------
__global__ __launch_bounds__(256) void k_count(const int* __restrict__ col,
                                               unsigned* __restrict__ cnt, int E) {
    int e = blockIdx.x * 256 + threadIdx.x;
    if (e < E) atomicAdd(&cnt[col[e]], 1u);
}

__global__ __launch_bounds__(256) void k_dinv(const unsigned* __restrict__ cnt,
                                              float* __restrict__ dinv, int N) {
    int n = blockIdx.x * 256 + threadIdx.x;
    if (n < N) dinv[n] = rsqrtf((float)cnt[n] + 2.0f);
}

// ---------------- exclusive scan (3 kernels, 1024-elem chunks) ----------------
__global__ __launch_bounds__(256) void k_chunk_sum(const unsigned* __restrict__ cnt, int N,
                                                   unsigned* __restrict__ bsum) {
    __shared__ unsigned ls[256];
    int base = blockIdx.x * 1024;
    unsigned s = 0;
    for (int i = threadIdx.x; i < 1024; i += 256) {
        int idx = base + i;
        if (idx < N) s += cnt[idx];
    }
    ls[threadIdx.x] = s;
    __syncthreads();
    for (int st = 128; st > 0; st >>= 1) {
        if (threadIdx.x < st) ls[threadIdx.x] += ls[threadIdx.x + st];
        __syncthreads();
    }
    if (threadIdx.x == 0) bsum[blockIdx.x] = ls[0];
}

__global__ void k_scan_bsum(unsigned* __restrict__ bsum, int nb) {
    if (threadIdx.x == 0 && blockIdx.x == 0) {
        unsigned acc = 0;
        for (int i = 0; i < nb; i++) { unsigned v = bsum[i]; bsum[i] = acc; acc += v; }
    }
}

__global__ __launch_bounds__(256) void k_scan_chunks(const unsigned* __restrict__ cnt, int N,
                                                     const unsigned* __restrict__ bsum,
                                                     int* __restrict__ off, int E) {
    __shared__ unsigned ls[256];
    int base = blockIdx.x * 1024;
    unsigned v[4];
    unsigned s = 0;
#pragma unroll
    for (int j = 0; j < 4; j++) {
        int idx = base + threadIdx.x * 4 + j;
        v[j] = (idx < N) ? cnt[idx] : 0u;
        s += v[j];
    }
    ls[threadIdx.x] = s;
    __syncthreads();
    if (threadIdx.x == 0) {
        unsigned acc = bsum[blockIdx.x];
        for (int i = 0; i < 256; i++) { unsigned t = ls[i]; ls[i] = acc; acc += t; }
    }
    __syncthreads();
    unsigned acc = ls[threadIdx.x];
#pragma unroll
    for (int j = 0; j < 4; j++) {
        int idx = base + threadIdx.x * 4 + j;
        if (idx < N) off[idx] = (int)acc;
        acc += v[j];
    }
    if (base + threadIdx.x * 4 <= N - 1 && N - 1 < base + threadIdx.x * 4 + 4) off[N] = E;
}

// ---------------- counting-sort placement: (row, norm) grouped by col ----------------
__global__ __launch_bounds__(256) void k_place(const int* __restrict__ row,
                                               const int* __restrict__ col,
                                               const float* __restrict__ dinv,
                                               int* __restrict__ cursor,
                                               int2* __restrict__ spack, int E) {
    int e = blockIdx.x * 256 + threadIdx.x;
    if (e >= E) return;
    int r = row[e], c = col[e];
    int pos = atomicAdd(&cursor[c], 1);
    spack[pos] = make_int2(r, __float_as_int(dinv[r] * dinv[c]));
}

// ---------------- GEMM: Y[N,128] = X[N,128] @ W[128,128] ----------------
// MODE 0: f32 in           -> bf16 out
// MODE 1: f32 in, BN+leaky -> bf16 out
// MODE 2: f32 in, +bias    -> f32 out
template <int MODE>
__global__ __launch_bounds__(256) void k_gemm_t(const float* __restrict__ X,
                                                const float* __restrict__ W,
                                                const float* __restrict__ sums, float invN,
                                                const float* __restrict__ bnw,
                                                const float* __restrict__ bnb,
                                                const float* __restrict__ bias,
                                                void* __restrict__ Yv, int N) {
    __shared__ float xs[64][132];
    __shared__ float sc[128], sb[128];
    const int tid = threadIdx.x;
    if (MODE == 1) {
        if (tid < 128) {
            float mu = sums[tid] * invN;
            float var = sums[128 + tid] * invN - mu * mu;
            float s = rsqrtf(var + EPSV) * bnw[tid];
            sc[tid] = s;
            sb[tid] = bnb[tid] - mu * s;
        }
        __syncthreads();
    }
    const int base = blockIdx.x * 64;
    for (int i = tid; i < 2048; i += 256) {
        int r = i >> 5, c4 = i & 31;
        int row = base + r; if (row >= N) row = N - 1;
        float4 v = ((const float4*)(X + (size_t)row * 128))[c4];
        if (MODE == 1) {
            int f = c4 * 4;
            v.x = fmaf(v.x, sc[f + 0], sb[f + 0]); v.x = v.x > 0.f ? v.x : SLOPE * v.x;
            v.y = fmaf(v.y, sc[f + 1], sb[f + 1]); v.y = v.y > 0.f ? v.y : SLOPE * v.y;
            v.z = fmaf(v.z, sc[f + 2], sb[f + 2]); v.z = v.z > 0.f ? v.z : SLOPE * v.z;
            v.w = fmaf(v.w, sc[f + 3], sb[f + 3]); v.w = v.w > 0.f ? v.w : SLOPE * v.w;
        }
        *(float4*)(&xs[r][c4 * 4]) = v;
    }
    __syncthreads();
    const int c0 = (tid & 31) * 4;
    const int rg = tid >> 5;
    float acc[8][4];
#pragma unroll
    for (int i = 0; i < 8; i++) { acc[i][0] = acc[i][1] = acc[i][2] = acc[i][3] = 0.f; }
    for (int k = 0; k < 128; k += 4) {
        float4 w0 = *(const float4*)(W + (size_t)(k + 0) * 128 + c0);
        float4 w1 = *(const float4*)(W + (size_t)(k + 1) * 128 + c0);
        float4 w2 = *(const float4*)(W + (size_t)(k + 2) * 128 + c0);
        float4 w3 = *(const float4*)(W + (size_t)(k + 3) * 128 + c0);
#pragma unroll
        for (int i = 0; i < 8; i++) {
            float4 a = *(const float4*)(&xs[rg + 8 * i][k]);
            acc[i][0] = fmaf(a.x, w0.x, fmaf(a.y, w1.x, fmaf(a.z, w2.x, fmaf(a.w, w3.x, acc[i][0]))));
            acc[i][1] = fmaf(a.x, w0.y, fmaf(a.y, w1.y, fmaf(a.z, w2.y, fmaf(a.w, w3.y, acc[i][1]))));
            acc[i][2] = fmaf(a.x, w0.z, fmaf(a.y, w1.z, fmaf(a.z, w2.z, fmaf(a.w, w3.z, acc[i][2]))));
            acc[i][3] = fmaf(a.x, w0.w, fmaf(a.y, w1.w, fmaf(a.z, w2.w, fmaf(a.w, w3.w, acc[i][3]))));
        }
    }
#pragma unroll
    for (int i = 0; i < 8; i++) {
        int row = base + rg + 8 * i;
        if (row < N) {
            if (MODE == 2) {
                float4 o = make_float4(acc[i][0] + bias[c0], acc[i][1] + bias[c0 + 1],
                                       acc[i][2] + bias[c0 + 2], acc[i][3] + bias[c0 + 3]);
                ((float4*)((float*)Yv + (size_t)row * 128))[tid & 31] = o;
            } else {
                ushort4 o;
                o.x = f2bf(acc[i][0]); o.y = f2bf(acc[i][1]);
                o.z = f2bf(acc[i][2]); o.w = f2bf(acc[i][3]);
                ((ushort4*)((unsigned short*)Yv + (size_t)row * 128))[tid & 31] = o;
            }
        }
    }
}

// ---------------- CSR aggregation: 16-lane group owns a node ----------------
// Batched gathers: 8 (or 4) row-gathers issued back-to-back before any use ->
// up to 8 outstanding gather instructions per group (vs 1 before).
// Fused epilogue: self-loop + bias + h write + BN stats. No atomics on h.
__global__ __launch_bounds__(256) void k_agg5(const unsigned short* __restrict__ xwh,
                                              const int* __restrict__ off,
                                              const int2* __restrict__ spack,
                                              const float* __restrict__ dinv,
                                              const float* __restrict__ bias,
                                              float* __restrict__ h,
                                              float* __restrict__ sums, int N) {
    __shared__ float ls1[128], ls2[128];
    const int tid = threadIdx.x;
    if (tid < 128) { ls1[tid] = 0.f; ls2[tid] = 0.f; }
    __syncthreads();

    const int q = tid & 15;
    const int grp = (blockIdx.x * 256 + tid) >> 4;
    const int nGrp = gridDim.x * 16;

    float bj[8];
#pragma unroll
    for (int j = 0; j < 8; j++) bj[j] = bias[q * 8 + j];
    float st1[8] = {0, 0, 0, 0, 0, 0, 0, 0};
    float st2[8] = {0, 0, 0, 0, 0, 0, 0, 0};

    for (int n = grp; n < N; n += nGrp) {
        const int s = off[n], e = off[n + 1];
        float a[8] = {0, 0, 0, 0, 0, 0, 0, 0};
        int i = s;
        // 8-deep batch: 8 independent gathers in flight
        for (; i + 8 <= e; i += 8) {
            int2 p0 = spack[i + 0], p1 = spack[i + 1], p2 = spack[i + 2], p3 = spack[i + 3];
            int2 p4 = spack[i + 4], p5 = spack[i + 5], p6 = spack[i + 6], p7 = spack[i + 7];
            ushort8v v0 = *(const ushort8v*)(xwh + (size_t)p0.x * 128 + q * 8);
            ushort8v v1 = *(const ushort8v*)(xwh + (size_t)p1.x * 128 + q * 8);
            ushort8v v2 = *(const ushort8v*)(xwh + (size_t)p2.x * 128 + q * 8);
            ushort8v v3 = *(const ushort8v*)(xwh + (size_t)p3.x * 128 + q * 8);
            ushort8v v4 = *(const ushort8v*)(xwh + (size_t)p4.x * 128 + q * 8);
            ushort8v v5 = *(const ushort8v*)(xwh + (size_t)p5.x * 128 + q * 8);
            ushort8v v6 = *(const ushort8v*)(xwh + (size_t)p6.x * 128 + q * 8);
            ushort8v v7 = *(const ushort8v*)(xwh + (size_t)p7.x * 128 + q * 8);
            float n0 = __int_as_float(p0.y), n1 = __int_as_float(p1.y);
            float n2 = __int_as_float(p2.y), n3 = __int_as_float(p3.y);
            float n4 = __int_as_float(p4.y), n5 = __int_as_float(p5.y);
            float n6 = __int_as_float(p6.y), n7 = __int_as_float(p7.y);
#pragma unroll
            for (int j = 0; j < 8; j++) {
                float t = fmaf(n0, bf2f(v0[j]), fmaf(n1, bf2f(v1[j]),
                          fmaf(n2, bf2f(v2[j]), n3 * bf2f(v3[j]))));
                float u = fmaf(n4, bf2f(v4[j]), fmaf(n5, bf2f(v5[j]),
                          fmaf(n6, bf2f(v6[j]), n7 * bf2f(v7[j]))));
                a[j] += t + u;
            }
        }
        // 4-deep batch
        for (; i + 4 <= e; i += 4) {
            int2 p0 = spack[i + 0], p1 = spack[i + 1], p2 = spack[i + 2], p3 = spack[i + 3];
            ushort8v v0 = *(const ushort8v*)(xwh + (size_t)p0.x * 128 + q * 8);
            ushort8v v1 = *(const ushort8v*)(xwh + (size_t)p1.x * 128 + q * 8);
            ushort8v v2 = *(const ushort8v*)(xwh + (size_t)p2.x * 128 + q * 8);
            ushort8v v3 = *(const ushort8v*)(xwh + (size_t)p3.x * 128 + q * 8);
            float n0 = __int_as_float(p0.y), n1 = __int_as_float(p1.y);
            float n2 = __int_as_float(p2.y), n3 = __int_as_float(p3.y);
#pragma unroll
            for (int j = 0; j < 8; j++) {
                a[j] += fmaf(n0, bf2f(v0[j]), fmaf(n1, bf2f(v1[j]),
                        fmaf(n2, bf2f(v2[j]), n3 * bf2f(v3[j]))));
            }
        }
        // tail
        for (; i < e; ++i) {
            int2 p = spack[i];
            ushort8v v = *(const ushort8v*)(xwh + (size_t)p.x * 128 + q * 8);
            float nm = __int_as_float(p.y);
#pragma unroll
            for (int j = 0; j < 8; j++) a[j] = fmaf(nm, bf2f(v[j]), a[j]);
        }
        // epilogue: self-loop + bias, write h row, BN stats
        float dc = dinv[n];
        float sl = 2.f * dc * dc;
        ushort8v xv = *(const ushort8v*)(xwh + (size_t)n * 128 + q * 8);
        float o[8];
#pragma unroll
        for (int j = 0; j < 8; j++) {
            o[j] = fmaf(sl, bf2f(xv[j]), a[j]) + bj[j];
            st1[j] += o[j];
            st2[j] += o[j] * o[j];
        }
        float4* hp = (float4*)(h + (size_t)n * 128 + q * 8);
        hp[0] = make_float4(o[0], o[1], o[2], o[3]);
        hp[1] = make_float4(o[4], o[5], o[6], o[7]);
    }
#pragma unroll
    for (int j = 0; j < 8; j++) {
        atomicAdd(&ls1[q * 8 + j], st1[j]);
        atomicAdd(&ls2[q * 8 + j], st2[j]);
    }
    __syncthreads();
    if (tid < 128) {
        atomicAdd(&sums[tid], ls1[tid]);
        atomicAdd(&sums[128 + tid], ls2[tid]);
    }
}

// ---------------- pooling with fused BN2 + leaky ----------------
__global__ __launch_bounds__(256) void k_pool_init(unsigned* __restrict__ p, int total) {
    int i = blockIdx.x * 256 + threadIdx.x;
    if (i < total) p[i] = 0x007FFFFFu;  // encoded -inf
}

__device__ inline unsigned enc_f(float x) {
    unsigned u = __float_as_uint(x);
    return (u & 0x80000000u) ? ~u : (u | 0x80000000u);
}

__global__ __launch_bounds__(256) void k_pool2(const float* __restrict__ h,
                                               const int* __restrict__ batch,
                                               const float* __restrict__ sums, float invN,
                                               const float* __restrict__ bnw,
                                               const float* __restrict__ bnb,
                                               unsigned* __restrict__ pooled, int N) {
    const int f = threadIdx.x & 127;
    const int half = threadIdx.x >> 7;
    float mu = sums[f] * invN;
    float var = sums[128 + f] * invN - mu * mu;
    float scale = rsqrtf(var + EPSV) * bnw[f];
    float bias = bnb[f] - mu * scale;
    const int base = blockIdx.x * 128;
    const int end = min(base + 128, N);
    float m = -__builtin_inff();
    int g = -1;
    for (int n = base + half; n < end; n += 2) {
        int bg = batch[n];
        if (bg != g) {
            if (g >= 0) atomicMax(&pooled[(size_t)g * 128 + f], enc_f(m));
            g = bg;
            m = -__builtin_inff();
        }
        float v = fmaf(h[(size_t)n * 128 + f], scale, bias);
        v = v > 0.f ? v : SLOPE * v;
        m = fmaxf(m, v);
    }
    if (g >= 0) atomicMax(&pooled[(size_t)g * 128 + f], enc_f(m));
}

__global__ __launch_bounds__(256) void k_decode(unsigned* __restrict__ p, int total) {
    int i = blockIdx.x * 256 + threadIdx.x;
    if (i >= total) return;
    unsigned u = p[i];
    float v;
    if (u == 0x007FFFFFu) v = 0.f;  // empty graph (-inf) -> 0
    else if (u & 0x80000000u) v = __uint_as_float(u & 0x7FFFFFFFu);
    else v = __uint_as_float(~u);
    p[i] = __float_as_uint(v);
}

extern "C" void kernel_launch(void* const* d_in, const int* in_sizes, int n_in,
                              void* d_out, int out_size, void* d_ws, size_t ws_size,
                              hipStream_t stream) {
    const float* x     = (const float*)d_in[0];
    const int*   ei    = (const int*)d_in[1];
    const int*   batch = (const int*)d_in[2];
    const float* W1    = (const float*)d_in[3];
    const float* b1    = (const float*)d_in[4];
    const float* bn1w  = (const float*)d_in[5];
    const float* bn1b  = (const float*)d_in[6];
    const float* W2    = (const float*)d_in[7];
    const float* b2    = (const float*)d_in[8];
    const float* bn2w  = (const float*)d_in[9];
    const float* bn2b  = (const float*)d_in[10];
    const float* Wf    = (const float*)d_in[11];
    const float* bf    = (const float*)d_in[12];

    const int N = in_sizes[0] / 128;
    const int E = in_sizes[1] / 2;
    const int G = out_size / 128;
    const int* rowp = ei;
    const int* colp = ei + E;
    float* out = (float*)d_out;
    const float invN = 1.0f / N;

    char* w = (char*)d_ws;
    unsigned short* bufAh = (unsigned short*)w; w += (size_t)N * 128 * 2;  // bf16 xw
    float*    bufB   = (float*)w;    w += (size_t)N * 128 * 4;             // f32 h
    float*    dinv   = (float*)w;    w += (size_t)N * 4;
    unsigned* cnt    = (unsigned*)w; w += (size_t)N * 4;                   // reused as cursor
    int*      off    = (int*)w;      w += (size_t)(N + 4) * 4;
    unsigned* bsum   = (unsigned*)w; w += 1024 * 4;
    int2*     spack  = (int2*)w;     w += (size_t)E * 8;
    float*    sums   = (float*)w;    w += 512 * 4;                         // sums1 | sums2
    unsigned* pooled = (unsigned*)w; w += (size_t)G * 128 * 4;

    float* sums1 = sums;
    float* sums2 = sums + 256;
    const int nb = (N + 1023) / 1024;

    // ---- graph prep (once, reused by both layers) ----
    hipMemsetAsync(cnt, 0, (size_t)N * 4, stream);
    hipMemsetAsync(sums, 0, 512 * 4, stream);
    k_count<<<(E + 255) / 256, 256, 0, stream>>>(colp, cnt, E);
    k_dinv<<<(N + 255) / 256, 256, 0, stream>>>(cnt, dinv, N);
    k_chunk_sum<<<nb, 256, 0, stream>>>(cnt, N, bsum);
    k_scan_bsum<<<1, 64, 0, stream>>>(bsum, nb);
    k_scan_chunks<<<nb, 256, 0, stream>>>(cnt, N, bsum, off, E);
    hipMemcpyAsync(cnt, off, (size_t)N * 4, hipMemcpyDeviceToDevice, stream);  // cursor
    k_place<<<(E + 255) / 256, 256, 0, stream>>>(rowp, colp, dinv, (int*)cnt, spack, E);

    const int aggBlocks = 2048;

    // ---- layer 1 ----
    k_gemm_t<0><<<(N + 63) / 64, 256, 0, stream>>>(x, W1, nullptr, 0.f, nullptr, nullptr,
                                                   nullptr, bufAh, N);
    k_agg5<<<aggBlocks, 256, 0, stream>>>(bufAh, off, spack, dinv, b1, bufB, sums1, N);

    // ---- layer 2 (BN1 fused into GEMM staging) ----
    k_gemm_t<1><<<(N + 63) / 64, 256, 0, stream>>>(bufB, W2, sums1, invN, bn1w, bn1b,
                                                   nullptr, bufAh, N);
    k_agg5<<<aggBlocks, 256, 0, stream>>>(bufAh, off, spack, dinv, b2, bufB, sums2, N);

    // ---- pooling (BN2 fused) ----
    k_pool_init<<<(G * 128 + 255) / 256, 256, 0, stream>>>(pooled, G * 128);
    k_pool2<<<(N + 127) / 128, 256, 0, stream>>>(bufB, batch, sums2, invN, bn2w, bn2b,
                                                 pooled, N);
    k_decode<<<(G * 128 + 255) / 256, 256, 0, stream>>>(pooled, G * 128);

    // ---- final GEMM ----
    k_gemm_t<2><<<(G + 63) / 64, 256, 0, stream>>>((const float*)pooled, Wf, nullptr, 0.f,
                                                   nullptr, nullptr, bf, out, G);
}